// Round 7
// baseline (922.021 us; speedup 1.0000x reference)
//
#include <hip/hip_runtime.h>
#include <hip/hip_fp16.h>

// GCN: 4x GCNConv(relu) -> global_add_pool -> MLP(96->32 relu ->1)
// N=100000 nodes, E=1600000 edges, F=32, H=96, G=2048 graphs.
//
// R7: lane-request reduction. Evidence R3-R6: aggregate time is invariant at
// ~8.5G edges/s across byte/unroll/dtype changes => cost ~ 2-3 cyc per
// divergent lane-request at the per-CU TA. So: TPN=12 threads/node, each
// loading one uint4 (8 fp16 feats) => 12 req/edge (was 24). agg32: TPN=4.
// CSR rows padded to multiples of 4. Everything else per R6.

#define HIDDEN 96

__device__ inline float4 h4_to_f4(uint2 u) {
    __half2 a = *reinterpret_cast<__half2*>(&u.x);
    __half2 b = *reinterpret_cast<__half2*>(&u.y);
    float2 fa = __half22float2(a), fb = __half22float2(b);
    return make_float4(fa.x, fa.y, fb.x, fb.y);
}

__device__ inline uint2 f4_to_h4(float4 v) {
    __half2 a = __float22half2_rn(make_float2(v.x, v.y));
    __half2 b = __float22half2_rn(make_float2(v.z, v.w));
    uint2 u;
    u.x = *reinterpret_cast<unsigned*>(&a);
    u.y = *reinterpret_cast<unsigned*>(&b);
    return u;
}

__device__ inline int pad4(int c) { return (c + 3) & ~3; }

__global__ __launch_bounds__(256) void zero_int_kernel(int* p, int n) {
    int i = blockIdx.x * 256 + threadIdx.x;
    if (i < n) p[i] = 0;
}

__global__ __launch_bounds__(256) void zero_kernel(float* p, int n) {
    int i = blockIdx.x * 256 + threadIdx.x;
    if (i < n) p[i] = 0.0f;
}

// cast fp32 -> fp16, float4 granularity (n4 = count of float4s)
__global__ __launch_bounds__(256) void cast_h_kernel(const float4* __restrict__ in,
                                                     uint2* __restrict__ out, int n4) {
    int i = blockIdx.x * 256 + threadIdx.x;
    if (i < n4) out[i] = f4_to_h4(in[i]);
}

// in-degree histogram over dst; epos[e] = this edge's slot within its dst row
__global__ __launch_bounds__(256) void deg_pos_kernel(const int* __restrict__ dst,
                                                      int* __restrict__ cnt,
                                                      int* __restrict__ epos, int E) {
    int e = blockIdx.x * 256 + threadIdx.x;
    if (e < E) epos[e] = atomicAdd(&cnt[dst[e]], 1);
}

__global__ __launch_bounds__(256) void dinv_kernel(const int* __restrict__ cnt,
                                                   float* __restrict__ dinv, int n) {
    int i = blockIdx.x * 256 + threadIdx.x;
    if (i < n) dinv[i] = rsqrtf((float)(cnt[i] + 1));
}

// ---- 3-phase multi-block exclusive scan of pad4(cnt[0..N)) -> rowptr ----
__global__ __launch_bounds__(256) void scan_reduce_kernel(const int* __restrict__ cnt,
                                                          int* __restrict__ bsum, int N) {
    __shared__ int s[256];
    int b = blockIdx.x, tid = threadIdx.x;
    int base = b * 1024;
    int v = 0;
    for (int j = tid; j < 1024; j += 256) {
        int i = base + j;
        v += (i < N) ? pad4(cnt[i]) : 0;
    }
    s[tid] = v;
    __syncthreads();
    for (int off = 128; off > 0; off >>= 1) {
        if (tid < off) s[tid] += s[tid + off];
        __syncthreads();
    }
    if (tid == 0) bsum[b] = s[0];
}

__global__ __launch_bounds__(128) void scan_bsum_kernel(int* __restrict__ bsum, int nb) {
    __shared__ int s[128];
    int tid = threadIdx.x;
    int v = (tid < nb) ? bsum[tid] : 0;
    s[tid] = v;
    __syncthreads();
    for (int off = 1; off < 128; off <<= 1) {
        int t = (tid >= off) ? s[tid - off] : 0;
        __syncthreads();
        s[tid] += t;
        __syncthreads();
    }
    if (tid < nb) bsum[tid] = s[tid] - v;  // exclusive
}

// writes rowptr[0..N]; rowptr[N] = padded total (falls out of the scan)
__global__ __launch_bounds__(256) void scan_write_kernel(const int* __restrict__ cnt,
                                                         const int* __restrict__ bsum,
                                                         int* __restrict__ rowptr, int N) {
    __shared__ int ts[256];
    int b = blockIdx.x, tid = threadIdx.x;
    int base = b * 1024 + tid * 4;
    int v0 = (base + 0 < N) ? pad4(cnt[base + 0]) : 0;
    int v1 = (base + 1 < N) ? pad4(cnt[base + 1]) : 0;
    int v2 = (base + 2 < N) ? pad4(cnt[base + 2]) : 0;
    int v3 = (base + 3 < N) ? pad4(cnt[base + 3]) : 0;
    int sum = v0 + v1 + v2 + v3;
    ts[tid] = sum;
    __syncthreads();
    for (int off = 1; off < 256; off <<= 1) {
        int t = (tid >= off) ? ts[tid - off] : 0;
        __syncthreads();
        ts[tid] += t;
        __syncthreads();
    }
    int excl = bsum[b] + ts[tid] - sum;
    if (base + 0 <= N) rowptr[base + 0] = excl;
    if (base + 1 <= N) rowptr[base + 1] = excl + v0;
    if (base + 2 <= N) rowptr[base + 2] = excl + v0 + v1;
    if (base + 3 <= N) rowptr[base + 3] = excl + v0 + v1 + v2;
}

// Fill CSR slots (no atomics: slot position precomputed in epos).
// Padding slots stay col=0,val=0 (pre-zeroed) -> contribute exactly 0.
__global__ __launch_bounds__(256) void fill_csr_kernel(const int* __restrict__ src,
                                                       const int* __restrict__ dst,
                                                       const int* __restrict__ epos,
                                                       const float* __restrict__ dinv,
                                                       const int* __restrict__ rowptr,
                                                       int* __restrict__ col,
                                                       float* __restrict__ val, int E) {
    int e = blockIdx.x * 256 + threadIdx.x;
    if (e >= E) return;
    int s = src[e];
    int d = dst[e];
    int idx = rowptr[d] + epos[e];
    col[idx] = s;
    val[idx] = dinv[s] * dinv[d];
}

// Y[n x 96] = act(X[n x K]) @ W[K x 96] (+ b).  W in LDS (broadcast reads),
// one row per thread, 24 float4 accumulators. X and Y in fp16 (fp32 math).
template <int K, bool RELU, bool BIAS>
__global__ __launch_bounds__(256) void gemm_kernel(const uint2* __restrict__ X,
                                                   const float* __restrict__ W,
                                                   const float* __restrict__ b,
                                                   uint2* __restrict__ Y, int n) {
    __shared__ float wlds[K * HIDDEN];
    for (int idx = threadIdx.x; idx < K * HIDDEN; idx += 256) wlds[idx] = W[idx];
    __syncthreads();

    int row = blockIdx.x * 256 + threadIdx.x;
    if (row >= n) return;

    float4 acc[24];
#pragma unroll
    for (int j = 0; j < 24; j++) acc[j] = make_float4(0.f, 0.f, 0.f, 0.f);

    const float4* wl4 = reinterpret_cast<const float4*>(wlds);
    const uint2* xrow = X + (size_t)row * (K / 4);

    for (int k0 = 0; k0 < K; k0 += 4) {
        float4 xv = h4_to_f4(xrow[k0 >> 2]);
        if (RELU) {
            xv.x = fmaxf(xv.x, 0.f); xv.y = fmaxf(xv.y, 0.f);
            xv.z = fmaxf(xv.z, 0.f); xv.w = fmaxf(xv.w, 0.f);
        }
#pragma unroll
        for (int kk = 0; kk < 4; kk++) {
            float xs = (kk == 0) ? xv.x : (kk == 1) ? xv.y : (kk == 2) ? xv.z : xv.w;
#pragma unroll
            for (int j = 0; j < 24; j++) {
                float4 w = wl4[(k0 + kk) * 24 + j];
                acc[j].x += xs * w.x;
                acc[j].y += xs * w.y;
                acc[j].z += xs * w.z;
                acc[j].w += xs * w.w;
            }
        }
    }

    uint2* y2 = Y + (size_t)row * 24;
#pragma unroll
    for (int j = 0; j < 24; j++) {
        if (BIAS) {
            float4 bb = reinterpret_cast<const float4*>(b)[j];
            acc[j].x += bb.x; acc[j].y += bb.y; acc[j].z += bb.z; acc[j].w += bb.w;
        }
        y2[j] = f4_to_h4(acc[j]);
    }
}

// out[i] = dinv[i]^2*xw[i] (+ b) + sum_e val[e]*xw[col[e]], xw fp16.
// TPN threads/node, each owning 8 features = ONE uint4 (16B) load per edge
// -> TPN lane-requests per edge (the R3-R6 invariant says requests are the
// cost). Rows padded to multiples of 4 -> aligned int4/float4 col/val loads,
// 4-way unroll. fp32 accumulate (2x float4).
// POOL: atomicAdd relu(acc) into gpool[batch[i]] (fp32); else fp16 out.
template <int TPN, bool POOL, bool BIAS>
__global__ __launch_bounds__(256) void aggregate_kernel(const uint4* __restrict__ xwh,
                                                        const int* __restrict__ rowptr,
                                                        const int* __restrict__ col,
                                                        const float* __restrict__ val,
                                                        const float* __restrict__ dinv,
                                                        const float* __restrict__ b,
                                                        uint4* __restrict__ out,
                                                        const int* __restrict__ batch,
                                                        float* __restrict__ gpool, int n) {
    unsigned t = blockIdx.x * 256 + threadIdx.x;
    unsigned i = t / (unsigned)TPN, q = t % (unsigned)TPN;
    if (i >= (unsigned)n) return;

    float dv = dinv[i];
    float s = dv * dv;
    uint4 su = xwh[i * TPN + q];
    float4 sa = h4_to_f4(make_uint2(su.x, su.y));
    float4 sb = h4_to_f4(make_uint2(su.z, su.w));
    float4 accA = make_float4(s * sa.x, s * sa.y, s * sa.z, s * sa.w);
    float4 accB = make_float4(s * sb.x, s * sb.y, s * sb.z, s * sb.w);
    if (BIAS) {
        const float4* b4 = reinterpret_cast<const float4*>(b);
        float4 ba = b4[q * 2 + 0], bb = b4[q * 2 + 1];
        accA.x += ba.x; accA.y += ba.y; accA.z += ba.z; accA.w += ba.w;
        accB.x += bb.x; accB.y += bb.y; accB.z += bb.z; accB.w += bb.w;
    }

    int e = rowptr[i], end = rowptr[i + 1];
    for (; e < end; e += 4) {
        int4 c4 = *reinterpret_cast<const int4*>(col + e);
        float4 w4 = *reinterpret_cast<const float4*>(val + e);
        uint4 u0 = xwh[(unsigned)c4.x * TPN + q];
        uint4 u1 = xwh[(unsigned)c4.y * TPN + q];
        uint4 u2 = xwh[(unsigned)c4.z * TPN + q];
        uint4 u3 = xwh[(unsigned)c4.w * TPN + q];
        float4 a0 = h4_to_f4(make_uint2(u0.x, u0.y)), b0 = h4_to_f4(make_uint2(u0.z, u0.w));
        float4 a1 = h4_to_f4(make_uint2(u1.x, u1.y)), b1 = h4_to_f4(make_uint2(u1.z, u1.w));
        float4 a2 = h4_to_f4(make_uint2(u2.x, u2.y)), b2 = h4_to_f4(make_uint2(u2.z, u2.w));
        float4 a3 = h4_to_f4(make_uint2(u3.x, u3.y)), b3 = h4_to_f4(make_uint2(u3.z, u3.w));
        accA.x += w4.x * a0.x + w4.y * a1.x + w4.z * a2.x + w4.w * a3.x;
        accA.y += w4.x * a0.y + w4.y * a1.y + w4.z * a2.y + w4.w * a3.y;
        accA.z += w4.x * a0.z + w4.y * a1.z + w4.z * a2.z + w4.w * a3.z;
        accA.w += w4.x * a0.w + w4.y * a1.w + w4.z * a2.w + w4.w * a3.w;
        accB.x += w4.x * b0.x + w4.y * b1.x + w4.z * b2.x + w4.w * b3.x;
        accB.y += w4.x * b0.y + w4.y * b1.y + w4.z * b2.y + w4.w * b3.y;
        accB.z += w4.x * b0.z + w4.y * b1.z + w4.z * b2.z + w4.w * b3.z;
        accB.w += w4.x * b0.w + w4.y * b1.w + w4.z * b2.w + w4.w * b3.w;
    }

    if (POOL) {
        float* o = gpool + (size_t)batch[i] * (TPN * 8) + q * 8u;
        atomicAdd(o + 0, fmaxf(accA.x, 0.f));
        atomicAdd(o + 1, fmaxf(accA.y, 0.f));
        atomicAdd(o + 2, fmaxf(accA.z, 0.f));
        atomicAdd(o + 3, fmaxf(accA.w, 0.f));
        atomicAdd(o + 4, fmaxf(accB.x, 0.f));
        atomicAdd(o + 5, fmaxf(accB.y, 0.f));
        atomicAdd(o + 6, fmaxf(accB.z, 0.f));
        atomicAdd(o + 7, fmaxf(accB.w, 0.f));
    } else {
        uint2 ha = f4_to_h4(accA), hb = f4_to_h4(accB);
        out[i * TPN + q] = make_uint4(ha.x, ha.y, hb.x, hb.y);
    }
}

__global__ __launch_bounds__(64) void mlp_kernel(const float* __restrict__ g,
                                                 const float* __restrict__ Wf1,
                                                 const float* __restrict__ bf1,
                                                 const float* __restrict__ Wf2,
                                                 const float* __restrict__ bf2,
                                                 float* __restrict__ out, int G) {
    __shared__ float gs[HIDDEN];
    __shared__ float hid[32];
    int blk = blockIdx.x;
    int lane = threadIdx.x;
    for (int idx = lane; idx < HIDDEN; idx += 64) gs[idx] = g[(size_t)blk * HIDDEN + idx];
    __syncthreads();
    if (lane < 32) {
        float a = bf1[lane];
        for (int k = 0; k < HIDDEN; k++) a = fmaf(gs[k], Wf1[k * 32 + lane], a);
        hid[lane] = fmaxf(a, 0.f);
    }
    __syncthreads();
    if (lane == 0) {
        float o = bf2[0];
        for (int k = 0; k < 32; k++) o = fmaf(hid[k], Wf2[k], o);
        out[blk] = o;
    }
}

extern "C" void kernel_launch(void* const* d_in, const int* in_sizes, int n_in,
                              void* d_out, int out_size, void* d_ws, size_t ws_size,
                              hipStream_t stream) {
    const float* x     = (const float*)d_in[0];
    const int*   ei    = (const int*)d_in[1];
    const int*   batch = (const int*)d_in[2];
    const float* W1 = (const float*)d_in[3];  const float* b1 = (const float*)d_in[4];
    const float* W2 = (const float*)d_in[5];  const float* b2 = (const float*)d_in[6];
    const float* W3 = (const float*)d_in[7];  const float* b3 = (const float*)d_in[8];
    const float* W4 = (const float*)d_in[9];  const float* b4 = (const float*)d_in[10];
    const float* Wf1 = (const float*)d_in[11]; const float* bf1 = (const float*)d_in[12];
    const float* Wf2 = (const float*)d_in[13]; const float* bf2 = (const float*)d_in[14];
    float* out = (float*)d_out;

    int N = in_sizes[0] / 32;   // 100000
    int E = in_sizes[1] / 2;    // 1600000
    int G = out_size;           // 2048
    const int* src = ei;
    const int* dst = ei + E;
    int Emax = E + 4 * N;       // pad4-CSR upper bound (2.0M)

    // Workspace layout (~75 MB)
    char* ws = (char*)d_ws;
    size_t off = 0;
    auto alloc = [&](size_t bytes) -> void* {
        void* p = (void*)(ws + off);
        off += (bytes + 255) & ~(size_t)255;
        return p;
    };
    int*   degcnt = (int*)alloc((size_t)N * 4);
    float* dinv   = (float*)alloc((size_t)N * 4);
    int*   rowptr = (int*)alloc((size_t)(N + 1) * 4);
    int*   bsum   = (int*)alloc((size_t)128 * 4);
    int*   col    = (int*)alloc((size_t)Emax * 4);
    float* val    = (float*)alloc((size_t)Emax * 4);
    int*   epos   = (int*)alloc((size_t)E * 4);
    uint2* xh     = (uint2*)alloc((size_t)N * 32 * 2);      // x fp16
    uint4* aggXh  = (uint4*)alloc((size_t)N * 32 * 2);      // (A x) fp16
    uint4* bufB   = (uint4*)alloc((size_t)N * HIDDEN * 2);  // h fp16
    uint4* bufH   = (uint4*)alloc((size_t)N * HIDDEN * 2);  // xw fp16
    float* gbuf   = (float*)alloc((size_t)G * HIDDEN * 4);
    (void)ws_size;

    int gN   = (N + 255) / 256;
    int gE   = (E + 255) / 256;
    int gEm  = (Emax + 255) / 256;
    int gAgg32 = (int)(((long long)N * 4 + 255) / 256);
    int gAgg96 = (int)(((long long)N * 12 + 255) / 256);
    int nb   = (N + 1023) / 1024;   // 98 scan blocks (<= 128)

    // ---- CSR build (once per call) ----
    zero_int_kernel<<<gN, 256, 0, stream>>>(degcnt, N);
    zero_int_kernel<<<gEm, 256, 0, stream>>>(col, Emax);
    zero_kernel<<<gEm, 256, 0, stream>>>(val, Emax);
    deg_pos_kernel<<<gE, 256, 0, stream>>>(dst, degcnt, epos, E);
    dinv_kernel<<<gN, 256, 0, stream>>>(degcnt, dinv, N);
    scan_reduce_kernel<<<nb, 256, 0, stream>>>(degcnt, bsum, N);
    scan_bsum_kernel<<<1, 128, 0, stream>>>(bsum, nb);
    scan_write_kernel<<<nb, 256, 0, stream>>>(degcnt, bsum, rowptr, N);
    fill_csr_kernel<<<gE, 256, 0, stream>>>(src, dst, epos, dinv, rowptr, col, val, E);

    // ---- layer 1 reassociated: aggX = A x (32 feats), h1 = aggX W1 + b1 ----
    cast_h_kernel<<<(N * 8 + 255) / 256, 256, 0, stream>>>(
        reinterpret_cast<const float4*>(x), xh, N * 8);
    aggregate_kernel<4, false, false><<<gAgg32, 256, 0, stream>>>(
        reinterpret_cast<const uint4*>(xh), rowptr, col, val, dinv, nullptr,
        aggXh, nullptr, nullptr, N);
    gemm_kernel<32, false, true><<<gN, 256, 0, stream>>>(
        reinterpret_cast<const uint2*>(aggXh), W1, b1,
        reinterpret_cast<uint2*>(bufB), N);

    // ---- layers 2-3: xw = relu(h) W (fp16); h' = A xw + b (fp16) ----
    gemm_kernel<96, true, false><<<gN, 256, 0, stream>>>(
        reinterpret_cast<const uint2*>(bufB), W2, nullptr,
        reinterpret_cast<uint2*>(bufH), N);
    aggregate_kernel<12, false, true><<<gAgg96, 256, 0, stream>>>(
        bufH, rowptr, col, val, dinv, b2, bufB, nullptr, nullptr, N);

    gemm_kernel<96, true, false><<<gN, 256, 0, stream>>>(
        reinterpret_cast<const uint2*>(bufB), W3, nullptr,
        reinterpret_cast<uint2*>(bufH), N);
    aggregate_kernel<12, false, true><<<gAgg96, 256, 0, stream>>>(
        bufH, rowptr, col, val, dinv, b3, bufB, nullptr, nullptr, N);

    // ---- layer 4: aggregate fused with relu + global_add_pool (fp32) ----
    zero_kernel<<<(G * HIDDEN + 255) / 256, 256, 0, stream>>>(gbuf, G * HIDDEN);
    gemm_kernel<96, true, false><<<gN, 256, 0, stream>>>(
        reinterpret_cast<const uint2*>(bufB), W4, nullptr,
        reinterpret_cast<uint2*>(bufH), N);
    aggregate_kernel<12, true, true><<<gAgg96, 256, 0, stream>>>(
        bufH, rowptr, col, val, dinv, b4, nullptr, batch, gbuf, N);

    // ---- MLP head ----
    mlp_kernel<<<G, 64, 0, stream>>>(gbuf, Wf1, bf1, Wf2, bf2, out, G);
}